// Round 3
// baseline (2836.364 us; speedup 1.0000x reference)
//
#include <hip/hip_runtime.h>
#include <hip/hip_bf16.h>
#include <cstdint>

#define NTOK 8192
#define NEXP 8
#define HID  2048
#define INTR 5632
#define NT1  44     // INTR/128 n-tiles for gemm1
#define NT2  16     // HID/128  n-tiles for gemm2
#define MT_MAX 32   // max 256-row m-tiles per expert

typedef float f32x4  __attribute__((ext_vector_type(4)));
typedef short s16x8  __attribute__((ext_vector_type(8)));
typedef short s16x4  __attribute__((ext_vector_type(4)));

__device__ __forceinline__ short bfc(float f) {
  __hip_bfloat16 h = __float2bfloat16(f);
  return __builtin_bit_cast(short, h);
}
__device__ __forceinline__ s16x8 pk8(float4 a, float4 b) {
  s16x8 v;
  v[0]=bfc(a.x); v[1]=bfc(a.y); v[2]=bfc(a.z); v[3]=bfc(a.w);
  v[4]=bfc(b.x); v[5]=bfc(b.y); v[6]=bfc(b.z); v[7]=bfc(b.w);
  return v;
}
__device__ __forceinline__ s16x4 pk4(float4 a) {
  s16x4 v; v[0]=bfc(a.x); v[1]=bfc(a.y); v[2]=bfc(a.z); v[3]=bfc(a.w);
  return v;
}
__device__ __forceinline__ s16x8 cmb(s16x4 a, s16x4 b) {
  s16x8 v;
  v[0]=a[0]; v[1]=a[1]; v[2]=a[2]; v[3]=a[3];
  v[4]=b[0]; v[5]=b[1]; v[6]=b[2]; v[7]=b[3];
  return v;
}
__device__ __forceinline__ void gload16(const void* g, void* l) {
  __builtin_amdgcn_global_load_lds((const __attribute__((address_space(1))) void*)g,
                                   (__attribute__((address_space(3))) void*)l, 16, 0, 0);
}

#define TRREAD(dst, addr, IMM) \
  asm volatile("ds_read_b64_tr_b16 %0, %1 offset:" IMM : "=v"(dst) : "v"(addr))
#define DSR128(dst, addr, IMM) \
  asm volatile("ds_read_b128 %0, %1 offset:" IMM : "=v"(dst) : "v"(addr))
#define WAITLGKM(N) do { \
  asm volatile("s_waitcnt lgkmcnt(" #N ")" ::: "memory"); \
  __builtin_amdgcn_sched_barrier(0); } while (0)
#define DRAIN_BARRIER() \
  asm volatile("s_waitcnt vmcnt(0) lgkmcnt(0)\n\ts_barrier" ::: "memory")

#define MFMA_BF16 __builtin_amdgcn_mfma_f32_16x16x32_bf16

// ---------------- router: logits, softmax, top-2, compaction, x->bf16 ----------------
__global__ void router_kernel(const float* __restrict__ x, const float* __restrict__ wr,
                              int* __restrict__ cnt, int* __restrict__ lists,
                              float* __restrict__ wlists, __hip_bfloat16* __restrict__ xb) {
  const int wave = threadIdx.x >> 6;
  const int lane = threadIdx.x & 63;
  const int t = blockIdx.x * 4 + wave;
  if (t >= NTOK) return;
  float acc[NEXP];
#pragma unroll
  for (int e = 0; e < NEXP; e++) acc[e] = 0.f;
  const float* xrow = x + (size_t)t * HID;
  short* xbs = (short*)xb + (size_t)t * HID;
#pragma unroll
  for (int j = 0; j < HID / 256; j++) {
    const int k = j * 256 + lane * 4;
    float4 xv = *(const float4*)(xrow + k);
    *(s16x4*)(xbs + k) = pk4(xv);
#pragma unroll
    for (int e = 0; e < NEXP; e++) {
      float4 wv = *(const float4*)(wr + e * HID + k);
      acc[e] += xv.x * wv.x + xv.y * wv.y + xv.z * wv.z + xv.w * wv.w;
    }
  }
#pragma unroll
  for (int e = 0; e < NEXP; e++) {
    float v = acc[e];
    for (int off = 32; off; off >>= 1) v += __shfl_xor(v, off, 64);
    acc[e] = v;
  }
  if (lane == 0) {
    float m = acc[0];
#pragma unroll
    for (int e = 1; e < NEXP; e++) m = fmaxf(m, acc[e]);
    float p[NEXP], s = 0.f;
#pragma unroll
    for (int e = 0; e < NEXP; e++) { p[e] = __expf(acc[e] - m); s += p[e]; }
    const float inv = 1.f / s;
    int e1 = 0; float b1 = p[0];
#pragma unroll
    for (int e = 1; e < NEXP; e++) if (p[e] > b1) { b1 = p[e]; e1 = e; }
    int e2 = -1; float b2 = -1.f;
#pragma unroll
    for (int e = 0; e < NEXP; e++) if (e != e1 && p[e] > b2) { b2 = p[e]; e2 = e; }
    const int pos1 = atomicAdd(&cnt[e1], 1);
    lists[e1 * NTOK + pos1] = t; wlists[e1 * NTOK + pos1] = b1 * inv;
    const int pos2 = atomicAdd(&cnt[e2], 1);
    lists[e2 * NTOK + pos2] = t; wlists[e2 * NTOK + pos2] = b2 * inv;
  }
}

__global__ void offsets_kernel(const int* __restrict__ cnt, int* __restrict__ offs) {
  if (threadIdx.x == 0 && blockIdx.x == 0) {
    int o = 0;
#pragma unroll
    for (int e = 0; e < NEXP; e++) { offs[e] = o; o += cnt[e]; }
    offs[NEXP] = o;
  }
}

// ---------------- gemm1: h = silu(x@Wg) * (x@Wu) -> bf16 ----------------
__global__ __launch_bounds__(512, 1) void gemm1_kernel(
    const __hip_bfloat16* __restrict__ xb, const float* __restrict__ wg,
    const float* __restrict__ wu, const int* __restrict__ cnt,
    const int* __restrict__ offs, const int* __restrict__ lists,
    __hip_bfloat16* __restrict__ hbuf) {
  const int P = blockIdx.x;
  const int xcd = P & 7, slot = P >> 3;
  const int mt = slot & 31, jj = slot >> 5;
  const int g = jj * 8 + xcd;
  const int e = g / NT1, nt = g % NT1;
  const int count = cnt[e];
  if (mt * 256 >= count) return;
  const int n0 = nt * 128;
  const int lim = count - mt * 256;
  const int tid = threadIdx.x;
  const int w = tid >> 6, lane = tid & 63;
  const int wm = w >> 1, wn = w & 1;

  __shared__ short Ald[2][8192];
  __shared__ short Bgl[2][4096];
  __shared__ short Bul[2][4096];

  const int* tl = lists + e * NTOK + mt * 256;
  const short* xbs = (const short*)xb;
  const short* srcA0; const short* srcA1;
  {
    const int r0 = (w * 2 + 0) * 16 + (lane & 15);
    const int r1 = (w * 2 + 1) * 16 + (lane & 15);
    const int t0 = tl[r0 < lim ? r0 : 0];
    const int t1 = tl[r1 < lim ? r1 : 0];
    srcA0 = xbs + (size_t)t0 * HID + (lane >> 4) * 8;
    srcA1 = xbs + (size_t)t1 * HID + (lane >> 4) * 8;
  }
  const int kk = tid >> 4;            // 0..31 B-row in K-step
  const int c8 = (tid & 15) * 8;      // col base (8 cols/thread)
  const int bb = (c8 >> 4) * 512 + (((kk >> 2) & 1) * 4 + (kk >> 3)) * 64 + (kk & 3) * 16 + (c8 & 15);
  const float* pG = wg + (size_t)e * HID * INTR + (size_t)kk * INTR + n0 + c8;
  const float* pU = wu + (size_t)e * HID * INTR + (size_t)kk * INTR + n0 + c8;

  f32x4 accG[4][4], accU[4][4];
#pragma unroll
  for (int i = 0; i < 4; i++)
#pragma unroll
    for (int j = 0; j < 4; j++) {
      accG[i][j] = f32x4{0.f, 0.f, 0.f, 0.f};
      accU[i][j] = f32x4{0.f, 0.f, 0.f, 0.f};
    }

  // prologue: B(0) regs, A(0) -> buf0
  float4 g0 = ((const float4*)pG)[0], g1 = ((const float4*)pG)[1];
  float4 u0 = ((const float4*)pU)[0], u1 = ((const float4*)pU)[1];
  pG += 32 * (size_t)INTR; pU += 32 * (size_t)INTR;
  gload16(srcA0, &Ald[0][(w * 2 + 0) * 512]);
  gload16(srcA1, &Ald[0][(w * 2 + 1) * 512]);
  srcA0 += 32; srcA1 += 32;

#define MMQ(NF, TG, TU)                                                         \
  { s16x8 bg = cmb(TG[2*NF], TG[2*NF+1]), bu = cmb(TU[2*NF], TU[2*NF+1]);       \
    __builtin_amdgcn_s_setprio(1);                                              \
    accG[0][NF] = MFMA_BF16(af[0], bg, accG[0][NF], 0, 0, 0);                   \
    accU[0][NF] = MFMA_BF16(af[0], bu, accU[0][NF], 0, 0, 0);                   \
    accG[1][NF] = MFMA_BF16(af[1], bg, accG[1][NF], 0, 0, 0);                   \
    accU[1][NF] = MFMA_BF16(af[1], bu, accU[1][NF], 0, 0, 0);                   \
    accG[2][NF] = MFMA_BF16(af[2], bg, accG[2][NF], 0, 0, 0);                   \
    accU[2][NF] = MFMA_BF16(af[2], bu, accU[2][NF], 0, 0, 0);                   \
    accG[3][NF] = MFMA_BF16(af[3], bg, accG[3][NF], 0, 0, 0);                   \
    accU[3][NF] = MFMA_BF16(af[3], bu, accU[3][NF], 0, 0, 0);                   \
    __builtin_amdgcn_s_setprio(0); }

#define G1_BODY(PC, PN, STG)                                                    \
  {                                                                             \
    *(s16x8*)(&Bgl[PC][bb]) = pk8(g0, g1);                                      \
    *(s16x8*)(&Bul[PC][bb]) = pk8(u0, u1);                                      \
    DRAIN_BARRIER();                                                            \
    if (STG) {                                                                  \
      g0 = ((const float4*)pG)[0]; g1 = ((const float4*)pG)[1];                 \
      u0 = ((const float4*)pU)[0]; u1 = ((const float4*)pU)[1];                 \
      gload16(srcA0, &Ald[PN][(w * 2 + 0) * 512]);                              \
      gload16(srcA1, &Ald[PN][(w * 2 + 1) * 512]);                              \
      pG += 32 * (size_t)INTR; pU += 32 * (size_t)INTR;                         \
      srcA0 += 32; srcA1 += 32;                                                 \
    }                                                                           \
    const uint32_t bga = (uint32_t)(uintptr_t)&Bgl[PC][0] + wn * 4096 + lane * 8; \
    const uint32_t bua = (uint32_t)(uintptr_t)&Bul[PC][0] + wn * 4096 + lane * 8; \
    const uint32_t aad = (uint32_t)(uintptr_t)&Ald[PC][0] + wm * 4096 + lane * 16; \
    s16x4 tg[8], tu[8]; s16x8 af[4];                                            \
    TRREAD(tg[0], bga, "0");    TRREAD(tg[1], bga, "512");                      \
    TRREAD(tu[0], bua, "0");    TRREAD(tu[1], bua, "512");                      \
    DSR128(af[0], aad, "0");    DSR128(af[1], aad, "1024");                     \
    DSR128(af[2], aad, "2048"); DSR128(af[3], aad, "3072");                     \
    TRREAD(tg[2], bga, "1024"); TRREAD(tg[3], bga, "1536");                     \
    TRREAD(tu[2], bua, "1024"); TRREAD(tu[3], bua, "1536");                     \
    TRREAD(tg[4], bga, "2048"); TRREAD(tg[5], bga, "2560");                     \
    TRREAD(tu[4], bua, "2048"); TRREAD(tu[5], bua, "2560");                     \
    TRREAD(tg[6], bga, "3072"); TRREAD(tg[7], bga, "3584");                     \
    TRREAD(tu[6], bua, "3072"); TRREAD(tu[7], bua, "3584");                     \
    WAITLGKM(12);                                                               \
    MMQ(0, tg, tu)                                                              \
    WAITLGKM(8);                                                                \
    MMQ(1, tg, tu)                                                              \
    WAITLGKM(4);                                                                \
    MMQ(2, tg, tu)                                                              \
    WAITLGKM(0);                                                                \
    MMQ(3, tg, tu)                                                              \
  }

  for (int t = 0; t < 62; t += 2) {
    G1_BODY(0, 1, 1)
    G1_BODY(1, 0, 1)
  }
  G1_BODY(0, 1, 1)
  G1_BODY(1, 0, 0)
#undef G1_BODY
#undef MMQ

  const int hrow0 = offs[e] + mt * 256;
#pragma unroll
  for (int mf = 0; mf < 4; mf++) {
#pragma unroll
    for (int reg = 0; reg < 4; reg++) {
      const int row = wm * 64 + mf * 16 + (lane >> 4) * 4 + reg;
      if (row < lim) {
        __hip_bfloat16* hp = hbuf + (size_t)(hrow0 + row) * INTR + n0 + wn * 64 + (lane & 15);
#pragma unroll
        for (int nf = 0; nf < 4; nf++) {
          const float gv = accG[mf][nf][reg];
          const float uv = accU[mf][nf][reg];
          const float h = (gv / (1.f + __expf(-gv))) * uv;
          hp[nf * 16] = __float2bfloat16(h);
        }
      }
    }
  }
}

// ---------------- gemm2: out[tok] += (h @ Wd) * w_combine ----------------
__global__ __launch_bounds__(512, 1) void gemm2_kernel(
    const __hip_bfloat16* __restrict__ hbuf, const float* __restrict__ wd,
    const int* __restrict__ cnt, const int* __restrict__ offs,
    const int* __restrict__ lists, const float* __restrict__ wlists,
    float* __restrict__ out) {
  const int P = blockIdx.x;
  const int xcd = P & 7, slot = P >> 3;
  const int mt = slot & 31, jj = slot >> 5;
  const int g = jj * 8 + xcd;
  const int e = g >> 4, nt = g & 15;
  const int count = cnt[e];
  if (mt * 256 >= count) return;
  const int n0 = nt * 128;
  const int lim = count - mt * 256;
  const int tid = threadIdx.x;
  const int w = tid >> 6, lane = tid & 63;
  const int wm = w >> 1, wn = w & 1;

  __shared__ short Ald[2][8192];
  __shared__ short Bld[2][4096];

  const int sb = offs[e] + mt * 256;
  const short* hb = (const short*)hbuf;
  const short* srcA0; const short* srcA1;
  {
    int s0 = sb + (w * 2 + 0) * 16 + (lane & 15);
    int s1 = sb + (w * 2 + 1) * 16 + (lane & 15);
    if (s0 > 2 * NTOK - 1) s0 = 2 * NTOK - 1;
    if (s1 > 2 * NTOK - 1) s1 = 2 * NTOK - 1;
    srcA0 = hb + (size_t)s0 * INTR + (lane >> 4) * 8;
    srcA1 = hb + (size_t)s1 * INTR + (lane >> 4) * 8;
  }
  const int kk = tid >> 4;
  const int c8 = (tid & 15) * 8;
  const int bb = (c8 >> 4) * 512 + (((kk >> 2) & 1) * 4 + (kk >> 3)) * 64 + (kk & 3) * 16 + (c8 & 15);
  const float* pB = wd + (size_t)e * INTR * HID + (size_t)kk * HID + n0 + c8;

  f32x4 acc[4][4];
#pragma unroll
  for (int i = 0; i < 4; i++)
#pragma unroll
    for (int j = 0; j < 4; j++) acc[i][j] = f32x4{0.f, 0.f, 0.f, 0.f};

  float4 b0 = ((const float4*)pB)[0], b1 = ((const float4*)pB)[1];
  pB += 32 * (size_t)HID;
  gload16(srcA0, &Ald[0][(w * 2 + 0) * 512]);
  gload16(srcA1, &Ald[0][(w * 2 + 1) * 512]);
  srcA0 += 32; srcA1 += 32;

#define MMQ2(NF)                                                                \
  { s16x8 bf = cmb(tb[2*NF], tb[2*NF+1]);                                       \
    __builtin_amdgcn_s_setprio(1);                                              \
    acc[0][NF] = MFMA_BF16(af[0], bf, acc[0][NF], 0, 0, 0);                     \
    acc[1][NF] = MFMA_BF16(af[1], bf, acc[1][NF], 0, 0, 0);                     \
    acc[2][NF] = MFMA_BF16(af[2], bf, acc[2][NF], 0, 0, 0);                     \
    acc[3][NF] = MFMA_BF16(af[3], bf, acc[3][NF], 0, 0, 0);                     \
    __builtin_amdgcn_s_setprio(0); }

#define G2_BODY(PC, PN, STG)                                                    \
  {                                                                             \
    *(s16x8*)(&Bld[PC][bb]) = pk8(b0, b1);                                      \
    DRAIN_BARRIER();                                                            \
    if (STG) {                                                                  \
      b0 = ((const float4*)pB)[0]; b1 = ((const float4*)pB)[1];                 \
      gload16(srcA0, &Ald[PN][(w * 2 + 0) * 512]);                              \
      gload16(srcA1, &Ald[PN][(w * 2 + 1) * 512]);                              \
      pB += 32 * (size_t)HID;                                                   \
      srcA0 += 32; srcA1 += 32;                                                 \
    }                                                                           \
    const uint32_t ba  = (uint32_t)(uintptr_t)&Bld[PC][0] + wn * 4096 + lane * 8; \
    const uint32_t aad = (uint32_t)(uintptr_t)&Ald[PC][0] + wm * 4096 + lane * 16; \
    s16x4 tb[8]; s16x8 af[4];                                                   \
    TRREAD(tb[0], ba, "0");    TRREAD(tb[1], ba, "512");                        \
    DSR128(af[0], aad, "0");    DSR128(af[1], aad, "1024");                     \
    DSR128(af[2], aad, "2048"); DSR128(af[3], aad, "3072");                     \
    TRREAD(tb[2], ba, "1024"); TRREAD(tb[3], ba, "1536");                       \
    TRREAD(tb[4], ba, "2048"); TRREAD(tb[5], ba, "2560");                       \
    TRREAD(tb[6], ba, "3072"); TRREAD(tb[7], ba, "3584");                       \
    WAITLGKM(6);                                                                \
    MMQ2(0)                                                                     \
    WAITLGKM(4);                                                                \
    MMQ2(1)                                                                     \
    WAITLGKM(2);                                                                \
    MMQ2(2)                                                                     \
    WAITLGKM(0);                                                                \
    MMQ2(3)                                                                     \
  }

  for (int t = 0; t < 174; t += 2) {
    G2_BODY(0, 1, 1)
    G2_BODY(1, 0, 1)
  }
  G2_BODY(0, 1, 1)
  G2_BODY(1, 0, 0)
#undef G2_BODY
#undef MMQ2

  const int* tle = lists + e * NTOK + mt * 256;
  const float* wle = wlists + e * NTOK + mt * 256;
#pragma unroll
  for (int mf = 0; mf < 4; mf++) {
#pragma unroll
    for (int reg = 0; reg < 4; reg++) {
      const int row = wm * 64 + mf * 16 + (lane >> 4) * 4 + reg;
      if (row < lim) {
        const int tok = tle[row];
        const float wt = wle[row];
        float* op = out + (size_t)tok * HID + n0 + wn * 64 + (lane & 15);
#pragma unroll
        for (int nf = 0; nf < 4; nf++)
          atomicAdd(op + nf * 16, acc[mf][nf][reg] * wt);
      }
    }
  }
}

extern "C" void kernel_launch(void* const* d_in, const int* in_sizes, int n_in,
                              void* d_out, int out_size, void* d_ws, size_t ws_size,
                              hipStream_t stream) {
  const float* x  = (const float*)d_in[0];
  const float* wr = (const float*)d_in[1];
  const float* wg = (const float*)d_in[2];
  const float* wu = (const float*)d_in[3];
  const float* wd = (const float*)d_in[4];
  float* out = (float*)d_out;

  int* cnt    = (int*)d_ws;
  int* offs   = cnt + 8;
  int* lists  = cnt + 32;
  float* wlists = (float*)(lists + NEXP * NTOK);
  __hip_bfloat16* xbf  = (__hip_bfloat16*)((char*)d_ws + (1u << 20));
  __hip_bfloat16* hbuf = (__hip_bfloat16*)((char*)d_ws + (36u << 20));

  hipMemsetAsync(cnt, 0, 32 * sizeof(int), stream);
  hipMemsetAsync(out, 0, (size_t)NTOK * HID * sizeof(float), stream);

  router_kernel<<<NTOK / 4, 256, 0, stream>>>(x, wr, cnt, lists, wlists, xbf);
  offsets_kernel<<<1, 64, 0, stream>>>(cnt, offs);
  gemm1_kernel<<<NEXP * NT1 * MT_MAX, 512, 0, stream>>>(xbf, wg, wu, cnt, offs, lists, hbuf);
  gemm2_kernel<<<NEXP * NT2 * MT_MAX, 512, 0, stream>>>(hbuf, wd, cnt, offs, lists, wlists, out);
}

// Round 4
// 1964.179 us; speedup vs baseline: 1.4440x; 1.4440x over previous
//
#include <hip/hip_runtime.h>
#include <hip/hip_bf16.h>
#include <cstdint>

#define NTOK 8192
#define NEXP 8
#define HID  2048
#define INTR 5632
#define NT1  44     // INTR/128 n-tiles for gemm1
#define NT2  16     // HID/128  n-tiles for gemm2
#define MT_MAX 32   // max 256-row m-tiles per expert

// workspace layout (bytes)
#define XB_OFF 1048576u
#define WG_OFF 34603008u            // XB_OFF + 32MB xb
#define WBYTES 184549376u           // one weight tensor in bf16
#define WU_OFF (WG_OFF + WBYTES)
#define WD_OFF (WU_OFF + WBYTES)
#define H_OFF  (WD_OFF + WBYTES)

typedef float f32x4  __attribute__((ext_vector_type(4)));
typedef short s16x8  __attribute__((ext_vector_type(8)));
typedef short s16x4  __attribute__((ext_vector_type(4)));

__device__ __forceinline__ short bfc(float f) {
  __hip_bfloat16 h = __float2bfloat16(f);
  return __builtin_bit_cast(short, h);
}
__device__ __forceinline__ s16x4 pk4(float4 a) {
  s16x4 v; v[0]=bfc(a.x); v[1]=bfc(a.y); v[2]=bfc(a.z); v[3]=bfc(a.w);
  return v;
}
__device__ __forceinline__ void gload16(const void* g, void* l) {
  __builtin_amdgcn_global_load_lds((const __attribute__((address_space(1))) void*)g,
                                   (__attribute__((address_space(3))) void*)l, 16, 0, 0);
}

#define DSR128(dst, addr, IMM) \
  asm volatile("ds_read_b128 %0, %1 offset:" IMM : "=v"(dst) : "v"(addr))
#define WAITLGKM(N) do { \
  asm volatile("s_waitcnt lgkmcnt(" #N ")" ::: "memory"); \
  __builtin_amdgcn_sched_barrier(0); } while (0)
#define WAITVM(N) do { \
  asm volatile("s_waitcnt vmcnt(" #N ")" ::: "memory"); \
  __builtin_amdgcn_sched_barrier(0); } while (0)

#define MFMA_BF16 __builtin_amdgcn_mfma_f32_16x16x32_bf16

// ---------------- prep: f32 weights -> bf16 MFMA B-fragment layout ----------------
// dst frags: [e][kt][nf][512 shorts]; frag short idx = lane*8+j with
// lane = ((k&31)>>3)*16 + (n&15), j = k&7  (B-frag: col=lane&15, k=(lane>>4)*8+j)
__global__ __launch_bounds__(256, 4) void prep_kernel(
    const float* __restrict__ src, short* __restrict__ dst,
    int KT, int NP, int Nsrc) {
  __shared__ float tile[32 * 132];
  const int b = blockIdx.x;
  const int np = b % NP;
  const int kt = (b / NP) % KT;
  const int e  = b / (NP * KT);
  const int tid = threadIdx.x;
  const float* s = src + (size_t)e * KT * 32 * (size_t)Nsrc + (size_t)kt * 32 * Nsrc + np * 128;
#pragma unroll
  for (int i = 0; i < 4; i++) {
    const int idx = tid + i * 256;        // 0..1023 float4s
    const int row = idx >> 5, c4 = idx & 31;
    float4 v = *(const float4*)(s + (size_t)row * Nsrc + c4 * 4);
    *(float4*)(tile + row * 132 + c4 * 4) = v;
  }
  __syncthreads();
  short* dbase = dst + ((size_t)(e * KT + kt) * (NP * 8) + np * 8) * 512;
#pragma unroll
  for (int i = 0; i < 2; i++) {
    const int c = tid + i * 256;          // 0..511 16B chunks
    const int lane = c & 63;
    const int nf = c >> 6;
    const int n = nf * 16 + (lane & 15);
    const int kb = (lane >> 4) * 8;
    s16x8 o;
#pragma unroll
    for (int j = 0; j < 8; j++) o[j] = bfc(tile[(kb + j) * 132 + n]);
    *(s16x8*)(dbase + (size_t)c * 8) = o;
  }
}

// ---------------- router: logits, softmax, top-2, compaction, x->bf16 ----------------
__global__ void router_kernel(const float* __restrict__ x, const float* __restrict__ wr,
                              int* __restrict__ cnt, int* __restrict__ lists,
                              float* __restrict__ wlists, __hip_bfloat16* __restrict__ xb) {
  const int wave = threadIdx.x >> 6;
  const int lane = threadIdx.x & 63;
  const int t = blockIdx.x * 4 + wave;
  if (t >= NTOK) return;
  float acc[NEXP];
#pragma unroll
  for (int e = 0; e < NEXP; e++) acc[e] = 0.f;
  const float* xrow = x + (size_t)t * HID;
  short* xbs = (short*)xb + (size_t)t * HID;
#pragma unroll
  for (int j = 0; j < HID / 256; j++) {
    const int k = j * 256 + lane * 4;
    float4 xv = *(const float4*)(xrow + k);
    *(s16x4*)(xbs + k) = pk4(xv);
#pragma unroll
    for (int e = 0; e < NEXP; e++) {
      float4 wv = *(const float4*)(wr + e * HID + k);
      acc[e] += xv.x * wv.x + xv.y * wv.y + xv.z * wv.z + xv.w * wv.w;
    }
  }
#pragma unroll
  for (int e = 0; e < NEXP; e++) {
    float v = acc[e];
    for (int off = 32; off; off >>= 1) v += __shfl_xor(v, off, 64);
    acc[e] = v;
  }
  if (lane == 0) {
    float m = acc[0];
#pragma unroll
    for (int e = 1; e < NEXP; e++) m = fmaxf(m, acc[e]);
    float p[NEXP], s = 0.f;
#pragma unroll
    for (int e = 0; e < NEXP; e++) { p[e] = __expf(acc[e] - m); s += p[e]; }
    const float inv = 1.f / s;
    int e1 = 0; float b1 = p[0];
#pragma unroll
    for (int e = 1; e < NEXP; e++) if (p[e] > b1) { b1 = p[e]; e1 = e; }
    int e2 = -1; float b2 = -1.f;
#pragma unroll
    for (int e = 0; e < NEXP; e++) if (e != e1 && p[e] > b2) { b2 = p[e]; e2 = e; }
    const int pos1 = atomicAdd(&cnt[e1], 1);
    lists[e1 * NTOK + pos1] = t; wlists[e1 * NTOK + pos1] = b1 * inv;
    const int pos2 = atomicAdd(&cnt[e2], 1);
    lists[e2 * NTOK + pos2] = t; wlists[e2 * NTOK + pos2] = b2 * inv;
  }
}

__global__ void offsets_kernel(const int* __restrict__ cnt, int* __restrict__ offs) {
  if (threadIdx.x == 0 && blockIdx.x == 0) {
    int o = 0;
#pragma unroll
    for (int e = 0; e < NEXP; e++) { offs[e] = o; o += cnt[e]; }
    offs[NEXP] = o;
  }
}

// ---------------- gemm1: h = silu(x@Wg) * (x@Wu) -> bf16 ----------------
// 256x128 tile, 8 waves (4M x 2N). All staging via global_load_lds (A gather +
// prep'd bf16 B frags). Triple-buffered LDS (32KB/buf), one s_barrier/step,
// counted vmcnt (never 0 mid-loop), counted lgkm -> MFMA clusters.
__global__ __launch_bounds__(512, 1) void gemm1_kernel(
    const __hip_bfloat16* __restrict__ xb, const short* __restrict__ wgb,
    const short* __restrict__ wub, const int* __restrict__ cnt,
    const int* __restrict__ offs, const int* __restrict__ lists,
    __hip_bfloat16* __restrict__ hbuf) {
  const int P = blockIdx.x;
  const int xcd = P & 7, slot = P >> 3;
  const int mt = slot & 31, jj = slot >> 5;
  const int g = jj * 8 + xcd;
  const int e = g / NT1, nt = g % NT1;
  const int count = cnt[e];
  if (mt * 256 >= count) return;
  const int n0 = nt * 128;
  const int lim = count - mt * 256;
  const int tid = threadIdx.x;
  const int w = tid >> 6, lane = tid & 63;
  const int wm = w >> 1, wn = w & 1;

  // buffer: A[0..8191] shorts (16 frags), Bg[8192..12287], Bu[12288..16383]
  __shared__ short Lds[3 * 16384];
  short* rootA = &Lds[0];
  const uint32_t ldsbase = (uint32_t)(uintptr_t)rootA;

  const int* tl = lists + e * NTOK + mt * 256;
  const short* xbs = (const short*)xb;
  const short* srcA0; const short* srcA1;
  {
    const int r0 = (w * 2 + 0) * 16 + (lane & 15);
    const int r1 = (w * 2 + 1) * 16 + (lane & 15);
    const int t0 = tl[r0 < lim ? r0 : 0];
    const int t1 = tl[r1 < lim ? r1 : 0];
    srcA0 = xbs + (size_t)t0 * HID + (lane >> 4) * 8;
    srcA1 = xbs + (size_t)t1 * HID + (lane >> 4) * 8;
  }
  const short* srcBg = wgb + ((size_t)(e * 64) * 352 + nt * 8) * 512 + tid * 8;
  const short* srcBu = wub + ((size_t)(e * 64) * 352 + nt * 8) * 512 + tid * 8;

  const uint32_t roA = wm * 4096 + lane * 16;
  const uint32_t roB = 16384 + wn * 4096 + lane * 16;
  const uint32_t roU = 24576 + wn * 4096 + lane * 16;

  f32x4 accG[4][4], accU[4][4];
#pragma unroll
  for (int i = 0; i < 4; i++)
#pragma unroll
    for (int j = 0; j < 4; j++) {
      accG[i][j] = f32x4{0.f, 0.f, 0.f, 0.f};
      accU[i][j] = f32x4{0.f, 0.f, 0.f, 0.f};
    }

  uint32_t b0 = 0, b1 = 32768, b2 = 65536;

#define STG1(BOFF) do {                                                         \
    short* d = rootA + ((BOFF) >> 1);                                           \
    gload16(srcA0, d + (w * 2 + 0) * 512);                                      \
    gload16(srcA1, d + (w * 2 + 1) * 512);                                      \
    gload16(srcBg, d + 8192 + w * 512);                                         \
    gload16(srcBu, d + 12288 + w * 512);                                        \
    srcA0 += 32; srcA1 += 32; srcBg += 180224; srcBu += 180224; } while (0)

#define MMQ(NF)                                                                 \
  { __builtin_amdgcn_s_setprio(1);                                              \
    accG[0][NF] = MFMA_BF16(af[0], bgf[NF], accG[0][NF], 0, 0, 0);              \
    accU[0][NF] = MFMA_BF16(af[0], buf4[NF], accU[0][NF], 0, 0, 0);             \
    accG[1][NF] = MFMA_BF16(af[1], bgf[NF], accG[1][NF], 0, 0, 0);              \
    accU[1][NF] = MFMA_BF16(af[1], buf4[NF], accU[1][NF], 0, 0, 0);             \
    accG[2][NF] = MFMA_BF16(af[2], bgf[NF], accG[2][NF], 0, 0, 0);              \
    accU[2][NF] = MFMA_BF16(af[2], buf4[NF], accU[2][NF], 0, 0, 0);             \
    accG[3][NF] = MFMA_BF16(af[3], bgf[NF], accG[3][NF], 0, 0, 0);              \
    accU[3][NF] = MFMA_BF16(af[3], buf4[NF], accU[3][NF], 0, 0, 0);             \
    __builtin_amdgcn_s_setprio(0); }

#define G1_BODY(VM, DOSTG)                                                      \
  {                                                                             \
    WAITVM(VM);                                                                 \
    __builtin_amdgcn_s_barrier();                                               \
    const uint32_t rb = ldsbase + b0;                                           \
    s16x8 af[4], bgf[4], buf4[4];                                               \
    DSR128(bgf[0], rb + roB, "0");                                              \
    DSR128(buf4[0], rb + roU, "0");                                             \
    DSR128(af[0], rb + roA, "0");                                               \
    DSR128(af[1], rb + roA, "1024");                                            \
    DSR128(af[2], rb + roA, "2048");                                            \
    DSR128(af[3], rb + roA, "3072");                                            \
    DSR128(bgf[1], rb + roB, "1024");                                           \
    DSR128(buf4[1], rb + roU, "1024");                                          \
    DSR128(bgf[2], rb + roB, "2048");                                           \
    DSR128(buf4[2], rb + roU, "2048");                                          \
    DSR128(bgf[3], rb + roB, "3072");                                           \
    DSR128(buf4[3], rb + roU, "3072");                                          \
    if (DOSTG) { STG1(b2); }                                                    \
    WAITLGKM(6);                                                                \
    MMQ(0)                                                                      \
    WAITLGKM(4);                                                                \
    MMQ(1)                                                                      \
    WAITLGKM(2);                                                                \
    MMQ(2)                                                                      \
    WAITLGKM(0);                                                                \
    MMQ(3)                                                                      \
    const uint32_t rtmp = b0; b0 = b1; b1 = b2; b2 = rtmp;                      \
  }

  STG1(b0);
  STG1(b1);
  for (int t = 0; t < 62; ++t) G1_BODY(4, 1)
  G1_BODY(4, 0)
  G1_BODY(0, 0)
#undef G1_BODY
#undef MMQ
#undef STG1

  const int hrow0 = offs[e] + mt * 256;
#pragma unroll
  for (int mf = 0; mf < 4; mf++) {
#pragma unroll
    for (int reg = 0; reg < 4; reg++) {
      const int row = wm * 64 + mf * 16 + (lane >> 4) * 4 + reg;
      if (row < lim) {
        __hip_bfloat16* hp = hbuf + (size_t)(hrow0 + row) * INTR + n0 + wn * 64 + (lane & 15);
#pragma unroll
        for (int nf = 0; nf < 4; nf++) {
          const float gv = accG[mf][nf][reg];
          const float uv = accU[mf][nf][reg];
          const float h = (gv / (1.f + __expf(-gv))) * uv;
          hp[nf * 16] = __float2bfloat16(h);
        }
      }
    }
  }
}

// ---------------- gemm2: out[tok] += (h @ Wd) * w_combine ----------------
// m-grouped XCD swizzle: all 16 n-tiles of one m-tile on one XCD (h-row L2 reuse)
__global__ __launch_bounds__(512, 1) void gemm2_kernel(
    const __hip_bfloat16* __restrict__ hbuf, const short* __restrict__ wdb,
    const int* __restrict__ cnt, const int* __restrict__ offs,
    const int* __restrict__ lists, const float* __restrict__ wlists,
    float* __restrict__ out) {
  const int P = blockIdx.x;
  const int xcd = P & 7, r = P >> 3;
  const int nt = r & 15, emq = r >> 4;    // emq 0..31
  const int gm = emq * 8 + xcd;           // global m-tile 0..255
  const int e = gm >> 5, mt = gm & 31;
  const int count = cnt[e];
  if (mt * 256 >= count) return;
  const int n0 = nt * 128;
  const int lim = count - mt * 256;
  const int tid = threadIdx.x;
  const int w = tid >> 6, lane = tid & 63;
  const int wm = w >> 1, wn = w & 1;

  // buffer: A[0..8191] shorts, B[8192..12287]; stride 12288 shorts (24KB)
  __shared__ short Lds[3 * 12288];
  short* rootA = &Lds[0];
  const uint32_t ldsbase = (uint32_t)(uintptr_t)rootA;

  const int sb = offs[e] + mt * 256;
  const short* hb = (const short*)hbuf;
  const short* srcA0; const short* srcA1;
  {
    int s0 = sb + (w * 2 + 0) * 16 + (lane & 15);
    int s1 = sb + (w * 2 + 1) * 16 + (lane & 15);
    if (s0 > 2 * NTOK - 1) s0 = 2 * NTOK - 1;
    if (s1 > 2 * NTOK - 1) s1 = 2 * NTOK - 1;
    srcA0 = hb + (size_t)s0 * INTR + (lane >> 4) * 8;
    srcA1 = hb + (size_t)s1 * INTR + (lane >> 4) * 8;
  }
  const short* srcB = wdb + ((size_t)(e * 176) * 128 + nt * 8) * 512 + tid * 8;

  const uint32_t roA = wm * 4096 + lane * 16;
  const uint32_t roB = 16384 + wn * 4096 + lane * 16;

  f32x4 acc[4][4];
#pragma unroll
  for (int i = 0; i < 4; i++)
#pragma unroll
    for (int j = 0; j < 4; j++) acc[i][j] = f32x4{0.f, 0.f, 0.f, 0.f};

  uint32_t b0 = 0, b1 = 24576, b2 = 49152;

#define STG2(BOFF) do {                                                         \
    short* d = rootA + ((BOFF) >> 1);                                           \
    gload16(srcA0, d + (w * 2 + 0) * 512);                                      \
    gload16(srcA1, d + (w * 2 + 1) * 512);                                      \
    gload16(srcB, d + 8192 + w * 512);                                          \
    srcA0 += 32; srcA1 += 32; srcB += 65536; } while (0)

#define MMQ2(NF)                                                                \
  { __builtin_amdgcn_s_setprio(1);                                              \
    acc[0][NF] = MFMA_BF16(af[0], bf[NF], acc[0][NF], 0, 0, 0);                 \
    acc[1][NF] = MFMA_BF16(af[1], bf[NF], acc[1][NF], 0, 0, 0);                 \
    acc[2][NF] = MFMA_BF16(af[2], bf[NF], acc[2][NF], 0, 0, 0);                 \
    acc[3][NF] = MFMA_BF16(af[3], bf[NF], acc[3][NF], 0, 0, 0);                 \
    __builtin_amdgcn_s_setprio(0); }

#define G2_BODY(VM, DOSTG)                                                      \
  {                                                                             \
    WAITVM(VM);                                                                 \
    __builtin_amdgcn_s_barrier();                                               \
    const uint32_t rb = ldsbase + b0;                                           \
    s16x8 af[4], bf[4];                                                         \
    DSR128(bf[0], rb + roB, "0");                                               \
    DSR128(af[0], rb + roA, "0");                                               \
    DSR128(af[1], rb + roA, "1024");                                            \
    DSR128(af[2], rb + roA, "2048");                                            \
    DSR128(af[3], rb + roA, "3072");                                            \
    DSR128(bf[1], rb + roB, "1024");                                            \
    DSR128(bf[2], rb + roB, "2048");                                            \
    DSR128(bf[3], rb + roB, "3072");                                            \
    if (DOSTG) { STG2(b2); }                                                    \
    WAITLGKM(3);                                                                \
    MMQ2(0)                                                                     \
    WAITLGKM(2);                                                                \
    MMQ2(1)                                                                     \
    WAITLGKM(1);                                                                \
    MMQ2(2)                                                                     \
    WAITLGKM(0);                                                                \
    MMQ2(3)                                                                     \
    const uint32_t rtmp = b0; b0 = b1; b1 = b2; b2 = rtmp;                      \
  }

  STG2(b0);
  STG2(b1);
  for (int t = 0; t < 174; ++t) G2_BODY(3, 1)
  G2_BODY(3, 0)
  G2_BODY(0, 0)
#undef G2_BODY
#undef MMQ2
#undef STG2

  const int* tle = lists + e * NTOK + mt * 256;
  const float* wle = wlists + e * NTOK + mt * 256;
#pragma unroll
  for (int mf = 0; mf < 4; mf++) {
#pragma unroll
    for (int reg = 0; reg < 4; reg++) {
      const int row = wm * 64 + mf * 16 + (lane >> 4) * 4 + reg;
      if (row < lim) {
        const int tok = tle[row];
        const float wt = wle[row];
        float* op = out + (size_t)tok * HID + n0 + wn * 64 + (lane & 15);
#pragma unroll
        for (int nf = 0; nf < 4; nf++)
          atomicAdd(op + nf * 16, acc[mf][nf][reg] * wt);
      }
    }
  }
}

extern "C" void kernel_launch(void* const* d_in, const int* in_sizes, int n_in,
                              void* d_out, int out_size, void* d_ws, size_t ws_size,
                              hipStream_t stream) {
  const float* x  = (const float*)d_in[0];
  const float* wr = (const float*)d_in[1];
  const float* wg = (const float*)d_in[2];
  const float* wu = (const float*)d_in[3];
  const float* wd = (const float*)d_in[4];
  float* out = (float*)d_out;
  char* ws = (char*)d_ws;

  int* cnt    = (int*)ws;
  int* offs   = cnt + 8;
  int* lists  = cnt + 32;
  float* wlists = (float*)(lists + NEXP * NTOK);
  __hip_bfloat16* xbf = (__hip_bfloat16*)(ws + XB_OFF);
  short* wgb = (short*)(ws + WG_OFF);
  short* wub = (short*)(ws + WU_OFF);
  short* wdb = (short*)(ws + WD_OFF);
  __hip_bfloat16* hbuf = (__hip_bfloat16*)(ws + H_OFF);

  hipMemsetAsync(cnt, 0, 32 * sizeof(int), stream);
  hipMemsetAsync(out, 0, (size_t)NTOK * HID * sizeof(float), stream);

  router_kernel<<<NTOK / 4, 256, 0, stream>>>(x, wr, cnt, lists, wlists, xbf);
  offsets_kernel<<<1, 64, 0, stream>>>(cnt, offs);
  prep_kernel<<<NEXP * 64 * 44, 256, 0, stream>>>(wg, wgb, 64, 44, INTR);
  prep_kernel<<<NEXP * 64 * 44, 256, 0, stream>>>(wu, wub, 64, 44, INTR);
  prep_kernel<<<NEXP * 176 * 16, 256, 0, stream>>>(wd, wdb, 176, 16, HID);
  gemm1_kernel<<<NEXP * NT1 * MT_MAX, 512, 0, stream>>>(xbf, wgb, wub, cnt, offs, lists, hbuf);
  gemm2_kernel<<<NEXP * NT2 * MT_MAX, 512, 0, stream>>>(hbuf, wdb, cnt, offs, lists, wlists, out);
}

// Round 5
// 1752.155 us; speedup vs baseline: 1.6188x; 1.1210x over previous
//
#include <hip/hip_runtime.h>
#include <hip/hip_bf16.h>
#include <cstdint>

#define NTOK 8192
#define NEXP 8
#define HID  2048
#define INTR 5632
#define NT1  44     // INTR/128 n-tiles for gemm1
#define NT2  16     // HID/128  n-tiles for gemm2

// ws offsets (bytes)
#define TCNT_OFF    4096u
#define SLOT_OFF    65536u      // slotlist: 18432 ints
#define T2S_OFF     262144u     // tok2slot: 32768 ints
#define W2_OFF      393216u     // w2: 32768 floats
#define LISTS_OFF   524288u     // lists: 65536 ints
#define WL_OFF      786432u     // wlists: 65536 floats
#define WG_OFF      2097152u
#define WBYTES      184549376u
#define WU_OFF      (WG_OFF + WBYTES)
#define HF_OFF      (WU_OFF + WBYTES)
#define HFBYTES     207618048u  // 72 mtiles * 176 kt * 16 frags * 1024 B
#define XG_OFF      (HF_OFF + HFBYTES)   // xg (75.5MB) then reused as pout (75.5MB)

typedef float f32x4  __attribute__((ext_vector_type(4)));
typedef short s16x8  __attribute__((ext_vector_type(8)));
typedef short s16x4  __attribute__((ext_vector_type(4)));

__device__ __forceinline__ short bfc(float f) {
  __hip_bfloat16 h = __float2bfloat16(f);
  return __builtin_bit_cast(short, h);
}
__device__ __forceinline__ float b2f(short s) {
  unsigned u = ((unsigned)(unsigned short)s) << 16;
  return __builtin_bit_cast(float, u);
}
__device__ __forceinline__ s16x8 pk8(float4 a, float4 b) {
  s16x8 v;
  v[0]=bfc(a.x); v[1]=bfc(a.y); v[2]=bfc(a.z); v[3]=bfc(a.w);
  v[4]=bfc(b.x); v[5]=bfc(b.y); v[6]=bfc(b.z); v[7]=bfc(b.w);
  return v;
}
__device__ __forceinline__ void gload16(const void* g, void* l) {
  __builtin_amdgcn_global_load_lds((const __attribute__((address_space(1))) void*)g,
                                   (__attribute__((address_space(3))) void*)l, 16, 0, 0);
}

#define DSR128(dst, addr, IMM) \
  asm volatile("ds_read_b128 %0, %1 offset:" IMM : "=v"(dst) : "v"(addr))
#define WAITLGKM(N) do { \
  asm volatile("s_waitcnt lgkmcnt(" #N ")" ::: "memory"); \
  __builtin_amdgcn_sched_barrier(0); } while (0)
#define WAITVM(N) do { \
  asm volatile("s_waitcnt vmcnt(" #N ")" ::: "memory"); \
  __builtin_amdgcn_sched_barrier(0); } while (0)

#define MFMA_BF16 __builtin_amdgcn_mfma_f32_16x16x32_bf16

// ---------------- prep: f32 weights -> bf16 MFMA B-fragment layout ----------------
__global__ __launch_bounds__(256, 4) void prep_kernel(
    const float* __restrict__ src, short* __restrict__ dst,
    int KT, int NP, int Nsrc) {
  __shared__ float tile[32 * 132];
  const int b = blockIdx.x;
  const int np = b % NP;
  const int kt = (b / NP) % KT;
  const int e  = b / (NP * KT);
  const int tid = threadIdx.x;
  const float* s = src + (size_t)e * KT * 32 * (size_t)Nsrc + (size_t)kt * 32 * Nsrc + np * 128;
#pragma unroll
  for (int i = 0; i < 4; i++) {
    const int idx = tid + i * 256;
    const int row = idx >> 5, c4 = idx & 31;
    float4 v = *(const float4*)(s + (size_t)row * Nsrc + c4 * 4);
    *(float4*)(tile + row * 132 + c4 * 4) = v;
  }
  __syncthreads();
  short* dbase = dst + ((size_t)(e * KT + kt) * (NP * 8) + np * 8) * 512;
#pragma unroll
  for (int i = 0; i < 2; i++) {
    const int c = tid + i * 256;
    const int lane = c & 63;
    const int nf = c >> 6;
    const int n = nf * 16 + (lane & 15);
    const int kb = (lane >> 4) * 8;
    s16x8 o;
#pragma unroll
    for (int j = 0; j < 8; j++) o[j] = bfc(tile[(kb + j) * 132 + n]);
    *(s16x8*)(dbase + (size_t)c * 8) = o;
  }
}

// ---------------- router ----------------
__global__ void router_kernel(const float* __restrict__ x, const float* __restrict__ wr,
                              int* __restrict__ cnt, int* __restrict__ lists,
                              float* __restrict__ wlists) {
  const int wave = threadIdx.x >> 6;
  const int lane = threadIdx.x & 63;
  const int t = blockIdx.x * 4 + wave;
  if (t >= NTOK) return;
  float acc[NEXP];
#pragma unroll
  for (int e = 0; e < NEXP; e++) acc[e] = 0.f;
  const float* xrow = x + (size_t)t * HID;
#pragma unroll
  for (int j = 0; j < HID / 256; j++) {
    const int k = j * 256 + lane * 4;
    float4 xv = *(const float4*)(xrow + k);
#pragma unroll
    for (int e = 0; e < NEXP; e++) {
      float4 wv = *(const float4*)(wr + e * HID + k);
      acc[e] += xv.x * wv.x + xv.y * wv.y + xv.z * wv.z + xv.w * wv.w;
    }
  }
#pragma unroll
  for (int e = 0; e < NEXP; e++) {
    float v = acc[e];
    for (int off = 32; off; off >>= 1) v += __shfl_xor(v, off, 64);
    acc[e] = v;
  }
  if (lane == 0) {
    float m = acc[0];
#pragma unroll
    for (int e = 1; e < NEXP; e++) m = fmaxf(m, acc[e]);
    float p[NEXP], s = 0.f;
#pragma unroll
    for (int e = 0; e < NEXP; e++) { p[e] = __expf(acc[e] - m); s += p[e]; }
    const float inv = 1.f / s;
    int e1 = 0; float b1 = p[0];
#pragma unroll
    for (int e = 1; e < NEXP; e++) if (p[e] > b1) { b1 = p[e]; e1 = e; }
    int e2 = -1; float b2 = -1.f;
#pragma unroll
    for (int e = 0; e < NEXP; e++) if (e != e1 && p[e] > b2) { b2 = p[e]; e2 = e; }
    const int pos1 = atomicAdd(&cnt[e1], 1);
    lists[e1 * NTOK + pos1] = t; wlists[e1 * NTOK + pos1] = b1 * inv;
    const int pos2 = atomicAdd(&cnt[e2], 1);
    lists[e2 * NTOK + pos2] = t; wlists[e2 * NTOK + pos2] = b2 * inv;
  }
}

__global__ void offsets_kernel(const int* __restrict__ cnt, int* __restrict__ poffs) {
  if (threadIdx.x == 0 && blockIdx.x == 0) {
    int o = 0;
#pragma unroll
    for (int e = 0; e < NEXP; e++) { poffs[e] = o; o += ((cnt[e] + 255) >> 8) << 8; }
    poffs[NEXP] = o;
  }
}

// ---------------- slotmap: slot->tok, tok->2 slots + weights ----------------
__global__ void slotmap_kernel(const int* __restrict__ cnt, const int* __restrict__ poffs,
                               const int* __restrict__ lists, const float* __restrict__ wlists,
                               int* __restrict__ slotlist, int* __restrict__ tcnt,
                               int* __restrict__ tok2slot, float* __restrict__ w2) {
  const int e = blockIdx.x;
  const int c = cnt[e], base = poffs[e];
  for (int pos = threadIdx.x; pos < c; pos += blockDim.x) {
    const int tok = lists[e * NTOK + pos];
    const int slot = base + pos;
    slotlist[slot] = tok;
    const int j = atomicAdd(&tcnt[tok], 1);
    tok2slot[tok * 2 + j] = slot;
    w2[tok * 2 + j] = wlists[e * NTOK + pos];
  }
}

// ---------------- gather: x (f32) -> xg bf16 in A-fragment layout ----------------
__global__ __launch_bounds__(256, 4) void gather_kernel(
    const float* __restrict__ x, const int* __restrict__ slotlist,
    short* __restrict__ xg) {
  const int c = blockIdx.x * 256 + threadIdx.x;   // 16B-chunk id
  const int cl = c & 63;
  const int fragid = c >> 6;
  const int f = fragid & 15;
  const int kt = (fragid >> 4) & 63;
  const int gmt = fragid >> 10;                   // 0..71
  const int tok = slotlist[gmt * 256 + f * 16 + (cl & 15)];
  const float* s = x + (size_t)tok * HID + kt * 32 + (cl >> 4) * 8;
  float4 a = *(const float4*)s, b = *(const float4*)(s + 4);
  *(s16x8*)(xg + (size_t)c * 8) = pk8(a, b);
}

// ---------------- gemm1: h = silu(x@Wg)*(x@Wu) -> hfrag (gemm2 A-frag layout) --------
// 128x128 tile, 4 waves (2Mx2N), double-buffered LDS (24KB/buf), 2 blocks/CU.
__global__ __launch_bounds__(256, 2) void gemm1_kernel(
    const short* __restrict__ xg, const short* __restrict__ wgb,
    const short* __restrict__ wub, const int* __restrict__ cnt,
    const int* __restrict__ poffs, short* __restrict__ hfrag) {
  const int P = blockIdx.x;
  const int xcd = P & 7, slot = P >> 3;
  const int mt = slot & 63, jj = slot >> 6;
  const int g = jj * 8 + xcd;                    // 0..351, pinned to xcd
  const int e = g / NT1, nt = g % NT1;
  if (mt * 128 >= cnt[e]) return;
  const int gmt = (poffs[e] >> 8) + (mt >> 1);
  const int fhalf = (mt & 1) * 8;
  const int tid = threadIdx.x;
  const int w = tid >> 6, lane = tid & 63;
  const int wm = w >> 1, wn = w & 1;

  // per buffer (12288 shorts): A frags [0,4096), Bg [4096,8192), Bu [8192,12288)
  __shared__ __align__(16) short Lds[2 * 12288];
  const uint32_t ldsbase = (uint32_t)(uintptr_t)&Lds[0];

  const short* srcA  = xg  + (((size_t)gmt * 64) * 16 + fhalf + w * 2) * 512 + lane * 8;
  const short* srcBg = wgb + (((size_t)e * 64) * 352 + nt * 8 + w * 2) * 512 + lane * 8;
  const short* srcBu = wub + (((size_t)e * 64) * 352 + nt * 8 + w * 2) * 512 + lane * 8;

  const uint32_t roA = wm * 4096 + lane * 16;
  const uint32_t roB = 8192 + wn * 4096 + lane * 16;
  const uint32_t roU = 16384 + wn * 4096 + lane * 16;

  f32x4 accG[4][4], accU[4][4];
#pragma unroll
  for (int i = 0; i < 4; i++)
#pragma unroll
    for (int j = 0; j < 4; j++) {
      accG[i][j] = f32x4{0.f, 0.f, 0.f, 0.f};
      accU[i][j] = f32x4{0.f, 0.f, 0.f, 0.f};
    }

  uint32_t cur = 0;

#define STG1(BOFF) do {                                                         \
    short* d = (short*)Lds + ((BOFF) >> 1);                                     \
    gload16(srcA,        d + w * 1024);                                         \
    gload16(srcA + 512,  d + w * 1024 + 512);                                   \
    gload16(srcBg,       d + 4096 + w * 1024);                                  \
    gload16(srcBg + 512, d + 4096 + w * 1024 + 512);                            \
    gload16(srcBu,       d + 8192 + w * 1024);                                  \
    gload16(srcBu + 512, d + 8192 + w * 1024 + 512);                            \
    srcA += 8192; srcBg += 180224; srcBu += 180224; } while (0)

#define MMQ(NF)                                                                 \
  { __builtin_amdgcn_s_setprio(1);                                              \
    accG[0][NF] = MFMA_BF16(af[0], bgf[NF], accG[0][NF], 0, 0, 0);              \
    accU[0][NF] = MFMA_BF16(af[0], buf4[NF], accU[0][NF], 0, 0, 0);             \
    accG[1][NF] = MFMA_BF16(af[1], bgf[NF], accG[1][NF], 0, 0, 0);              \
    accU[1][NF] = MFMA_BF16(af[1], buf4[NF], accU[1][NF], 0, 0, 0);             \
    accG[2][NF] = MFMA_BF16(af[2], bgf[NF], accG[2][NF], 0, 0, 0);              \
    accU[2][NF] = MFMA_BF16(af[2], buf4[NF], accU[2][NF], 0, 0, 0);             \
    accG[3][NF] = MFMA_BF16(af[3], bgf[NF], accG[3][NF], 0, 0, 0);              \
    accU[3][NF] = MFMA_BF16(af[3], buf4[NF], accU[3][NF], 0, 0, 0);             \
    __builtin_amdgcn_s_setprio(0); }

#define G1_BODY(DOSTG)                                                          \
  {                                                                             \
    WAITVM(0);                                                                  \
    __builtin_amdgcn_s_barrier();                                               \
    const uint32_t rb = ldsbase + cur;                                          \
    s16x8 af[4], bgf[4], buf4[4];                                               \
    DSR128(bgf[0], rb + roB, "0");                                              \
    DSR128(buf4[0], rb + roU, "0");                                             \
    DSR128(af[0], rb + roA, "0");                                               \
    DSR128(af[1], rb + roA, "1024");                                            \
    DSR128(af[2], rb + roA, "2048");                                            \
    DSR128(af[3], rb + roA, "3072");                                            \
    DSR128(bgf[1], rb + roB, "1024");                                           \
    DSR128(buf4[1], rb + roU, "1024");                                          \
    DSR128(bgf[2], rb + roB, "2048");                                           \
    DSR128(buf4[2], rb + roU, "2048");                                          \
    DSR128(bgf[3], rb + roB, "3072");                                           \
    DSR128(buf4[3], rb + roU, "3072");                                          \
    if (DOSTG) { STG1(cur ^ 24576); }                                           \
    WAITLGKM(6);                                                                \
    MMQ(0)                                                                      \
    WAITLGKM(4);                                                                \
    MMQ(1)                                                                      \
    WAITLGKM(2);                                                                \
    MMQ(2)                                                                      \
    WAITLGKM(0);                                                                \
    MMQ(3)                                                                      \
    cur ^= 24576;                                                               \
  }

  STG1(0);
  for (int t = 0; t < 63; ++t) G1_BODY(1)
  G1_BODY(0)
#undef G1_BODY
#undef MMQ
#undef STG1

  // epilogue: silu-gate, LDS transpose 128x128 (pad 136), store in gemm2 A-frag layout
  short* tr = (short*)Lds;    // 128*136 = 17408 shorts (34.8 KB)
  __syncthreads();
#pragma unroll
  for (int mf = 0; mf < 4; mf++)
#pragma unroll
    for (int reg = 0; reg < 4; reg++) {
      const int row = wm * 64 + mf * 16 + (lane >> 4) * 4 + reg;
#pragma unroll
      for (int nf = 0; nf < 4; nf++) {
        const int col = wn * 64 + nf * 16 + (lane & 15);
        const float gv = accG[mf][nf][reg];
        const float uv = accU[mf][nf][reg];
        tr[row * 136 + col] = bfc((gv / (1.f + __expf(-gv))) * uv);
      }
    }
  __syncthreads();
  short* hb = hfrag + (((size_t)gmt * 176 + nt * 4) * 16 + fhalf) * 512;
#pragma unroll
  for (int i = 0; i < 8; i++) {
    const int c = tid + i * 256;          // 0..2047
    const int cl = c & 63;
    const int f7 = (c >> 6) & 7;
    const int ktl = c >> 9;               // 0..3
    const int rr = f7 * 16 + (cl & 15);
    s16x8 v = *(const s16x8*)(tr + rr * 136 + ktl * 32 + (cl >> 4) * 8);
    *(s16x8*)(hb + ((size_t)ktl * 16 + f7) * 512 + cl * 8) = v;
  }
}

// ---------------- gemm2: pout[slot] = h @ Wd (bf16 partials, no atomics) ------------
// 256x128 tile, 8 waves, double-buffered 24KB, 2 blocks/CU (<=128 regs).
__global__ __launch_bounds__(512, 4) void gemm2_kernel(
    const short* __restrict__ hfrag, const short* __restrict__ wdb,
    const int* __restrict__ cnt, const int* __restrict__ poffs,
    __hip_bfloat16* __restrict__ pout) {
  const int P = blockIdx.x;
  const int xcd = P & 7, r = P >> 3;
  const int nt = r & 15, emq = r >> 4;
  const int gm = emq * 8 + xcd;           // m-tile pinned to xcd
  const int e = gm >> 5, mt = gm & 31;
  if (mt * 256 >= cnt[e]) return;
  const int gmt = (poffs[e] >> 8) + mt;
  const int n0 = nt * 128;
  const int tid = threadIdx.x;
  const int w = tid >> 6, lane = tid & 63;
  const int wm = w >> 1, wn = w & 1;

  // per buffer (12288 shorts): A 16 frags [0,8192), B 8 frags [8192,12288)
  __shared__ __align__(16) short Lds[2 * 12288];
  const uint32_t ldsbase = (uint32_t)(uintptr_t)&Lds[0];

  const short* srcA = hfrag + (((size_t)gmt * 176) * 16 + w * 2) * 512 + lane * 8;
  const short* srcB = wdb + (((size_t)e * 176) * 128 + nt * 8) * 512 + tid * 8;

  const uint32_t roA = wm * 4096 + lane * 16;
  const uint32_t roB = 16384 + wn * 4096 + lane * 16;

  f32x4 acc[4][4];
#pragma unroll
  for (int i = 0; i < 4; i++)
#pragma unroll
    for (int j = 0; j < 4; j++) acc[i][j] = f32x4{0.f, 0.f, 0.f, 0.f};

  uint32_t cur = 0;

#define STG2(BOFF) do {                                                         \
    short* d = (short*)Lds + ((BOFF) >> 1);                                     \
    gload16(srcA,       d + w * 1024);                                          \
    gload16(srcA + 512, d + w * 1024 + 512);                                    \
    gload16(srcB,       d + 8192 + w * 512);                                    \
    srcA += 8192; srcB += 65536; } while (0)

#define MMQ2(NF)                                                                \
  { __builtin_amdgcn_s_setprio(1);                                              \
    acc[0][NF] = MFMA_BF16(af[0], bf[NF], acc[0][NF], 0, 0, 0);                 \
    acc[1][NF] = MFMA_BF16(af[1], bf[NF], acc[1][NF], 0, 0, 0);                 \
    acc[2][NF] = MFMA_BF16(af[2], bf[NF], acc[2][NF], 0, 0, 0);                 \
    acc[3][NF] = MFMA_BF16(af[3], bf[NF], acc[3][NF], 0, 0, 0);                 \
    __builtin_amdgcn_s_setprio(0); }

#define G2_BODY(DOSTG)                                                          \
  {                                                                             \
    WAITVM(0);                                                                  \
    __builtin_amdgcn_s_barrier();                                               \
    const uint32_t rb = ldsbase + cur;                                          \
    s16x8 af[4], bf[4];                                                         \
    DSR128(bf[0], rb + roB, "0");                                               \
    DSR128(af[0], rb + roA, "0");                                               \
    DSR128(af[1], rb + roA, "1024");                                            \
    DSR128(af[2], rb + roA, "2048");                                            \
    DSR128(af[3], rb + roA, "3072");                                            \
    DSR128(bf[1], rb + roB, "1024");                                            \
    DSR128(bf[2], rb + roB, "2048");                                            \
    DSR128(bf[3], rb + roB, "3072");                                            \
    if (DOSTG) { STG2(cur ^ 24576); }                                           \
    WAITLGKM(3);                                                                \
    MMQ2(0)                                                                     \
    WAITLGKM(2);                                                                \
    MMQ2(1)                                                                     \
    WAITLGKM(1);                                                                \
    MMQ2(2)                                                                     \
    WAITLGKM(0);                                                                \
    MMQ2(3)                                                                     \
    cur ^= 24576;                                                               \
  }

  STG2(0);
  for (int t = 0; t < 175; ++t) G2_BODY(1)
  G2_BODY(0)
#undef G2_BODY
#undef MMQ2
#undef STG2

  const int slotb = poffs[e] + mt * 256;
#pragma unroll
  for (int mf = 0; mf < 4; mf++) {
#pragma unroll
    for (int reg = 0; reg < 4; reg++) {
      const int row = wm * 64 + mf * 16 + (lane >> 4) * 4 + reg;
      __hip_bfloat16* op = pout + (size_t)(slotb + row) * HID + n0 + wn * 64 + (lane & 15);
#pragma unroll
      for (int nf = 0; nf < 4; nf++)
        op[nf * 16] = __float2bfloat16(acc[mf][nf][reg]);
    }
  }
}

// ---------------- combine: out[t] = w0*pout[s0] + w1*pout[s1] ----------------
__global__ __launch_bounds__(256, 8) void combine_kernel(
    const __hip_bfloat16* __restrict__ pout, const int* __restrict__ tok2slot,
    const float* __restrict__ w2, float* __restrict__ out) {
  const int t = blockIdx.x;
  const int s0 = tok2slot[2 * t], s1 = tok2slot[2 * t + 1];
  const float w0 = w2[2 * t], w1 = w2[2 * t + 1];
  const short* p0 = (const short*)pout + (size_t)s0 * HID;
  const short* p1 = (const short*)pout + (size_t)s1 * HID;
  float* o = out + (size_t)t * HID;
  const int i = threadIdx.x;            // 256 threads x 8 floats = 2048
  s16x8 a = *(const s16x8*)(p0 + i * 8);
  s16x8 b = *(const s16x8*)(p1 + i * 8);
  float4 r0, r1;
  r0.x = w0 * b2f(a[0]) + w1 * b2f(b[0]);
  r0.y = w0 * b2f(a[1]) + w1 * b2f(b[1]);
  r0.z = w0 * b2f(a[2]) + w1 * b2f(b[2]);
  r0.w = w0 * b2f(a[3]) + w1 * b2f(b[3]);
  r1.x = w0 * b2f(a[4]) + w1 * b2f(b[4]);
  r1.y = w0 * b2f(a[5]) + w1 * b2f(b[5]);
  r1.z = w0 * b2f(a[6]) + w1 * b2f(b[6]);
  r1.w = w0 * b2f(a[7]) + w1 * b2f(b[7]);
  *(float4*)(o + i * 8) = r0;
  *(float4*)(o + i * 8 + 4) = r1;
}

extern "C" void kernel_launch(void* const* d_in, const int* in_sizes, int n_in,
                              void* d_out, int out_size, void* d_ws, size_t ws_size,
                              hipStream_t stream) {
  const float* x  = (const float*)d_in[0];
  const float* wr = (const float*)d_in[1];
  const float* wg = (const float*)d_in[2];
  const float* wu = (const float*)d_in[3];
  const float* wd = (const float*)d_in[4];
  float* out = (float*)d_out;
  char* ws = (char*)d_ws;

  int* cnt      = (int*)ws;                    // 8 ints
  int* poffs    = (int*)(ws + 64);             // 9 ints
  int* tcnt     = (int*)(ws + TCNT_OFF);       // 8192 ints
  int* slotlist = (int*)(ws + SLOT_OFF);       // 18432 ints
  int* tok2slot = (int*)(ws + T2S_OFF);        // 32768 ints
  float* w2     = (float*)(ws + W2_OFF);       // 32768 floats
  int* lists    = (int*)(ws + LISTS_OFF);      // 8*8192 ints
  float* wlists = (float*)(ws + WL_OFF);       // 8*8192 floats
  short* wgb    = (short*)(ws + WG_OFF);
  short* wub    = (short*)(ws + WU_OFF);
  short* wdb    = (short*)(ws + WG_OFF);       // reuses wgb region (after gemm1)
  short* hfrag  = (short*)(ws + HF_OFF);
  short* xg     = (short*)(ws + XG_OFF);
  __hip_bfloat16* pout = (__hip_bfloat16*)(ws + XG_OFF);  // reuses xg region (after gemm1)

  hipMemsetAsync(ws, 0, 256, stream);
  hipMemsetAsync(ws + TCNT_OFF, 0, 32768, stream);
  hipMemsetAsync(ws + SLOT_OFF, 0, 73728, stream);

  router_kernel<<<NTOK / 4, 256, 0, stream>>>(x, wr, cnt, lists, wlists);
  offsets_kernel<<<1, 64, 0, stream>>>(cnt, poffs);
  slotmap_kernel<<<NEXP, 256, 0, stream>>>(cnt, poffs, lists, wlists, slotlist, tcnt, tok2slot, w2);
  gather_kernel<<<18432, 256, 0, stream>>>(x, slotlist, xg);
  prep_kernel<<<NEXP * 64 * 44, 256, 0, stream>>>(wg, wgb, 64, 44, INTR);
  prep_kernel<<<NEXP * 64 * 44, 256, 0, stream>>>(wu, wub, 64, 44, INTR);
  gemm1_kernel<<<8 * 64 * NT1, 256, 0, stream>>>(xg, wgb, wub, cnt, poffs, hfrag);
  prep_kernel<<<NEXP * 176 * 16, 256, 0, stream>>>(wd, wdb, 176, 16, HID);
  gemm2_kernel<<<8 * 16 * 32, 512, 0, stream>>>(hfrag, wdb, cnt, poffs, pout);
  combine_kernel<<<NTOK, 256, 0, stream>>>(pout, tok2slot, w2, out);
}

// Round 6
// 1669.754 us; speedup vs baseline: 1.6987x; 1.0493x over previous
//
#include <hip/hip_runtime.h>
#include <hip/hip_bf16.h>
#include <cstdint>

#define NTOK 8192
#define NEXP 8
#define HID  2048
#define INTR 5632
#define NT1  44     // INTR/128 n-tiles for gemm1
#define NT2  16     // HID/128  n-tiles for gemm2

// ws offsets (bytes)
#define TCNT_OFF    4096u
#define SLOT_OFF    65536u      // slotlist: 18432 ints
#define T2S_OFF     262144u     // tok2slot: 32768 ints
#define W2_OFF      393216u     // w2: 32768 floats
#define LISTS_OFF   524288u     // lists: 65536 ints
#define WL_OFF      786432u     // wlists: 65536 floats
#define WG_OFF      2097152u
#define WBYTES      184549376u
#define WU_OFF      (WG_OFF + WBYTES)
#define HF_OFF      (WU_OFF + WBYTES)
#define HFBYTES     207618048u  // 72 mtiles * 176 kt * 16 frags * 1024 B
#define XG_OFF      (HF_OFF + HFBYTES)   // xg (75.5MB) then reused as pout

typedef float f32x4  __attribute__((ext_vector_type(4)));
typedef short s16x8  __attribute__((ext_vector_type(8)));
typedef short s16x4  __attribute__((ext_vector_type(4)));

__device__ __forceinline__ short bfc(float f) {
  __hip_bfloat16 h = __float2bfloat16(f);
  return __builtin_bit_cast(short, h);
}
__device__ __forceinline__ float b2f(short s) {
  unsigned u = ((unsigned)(unsigned short)s) << 16;
  return __builtin_bit_cast(float, u);
}
__device__ __forceinline__ s16x8 pk8(float4 a, float4 b) {
  s16x8 v;
  v[0]=bfc(a.x); v[1]=bfc(a.y); v[2]=bfc(a.z); v[3]=bfc(a.w);
  v[4]=bfc(b.x); v[5]=bfc(b.y); v[6]=bfc(b.z); v[7]=bfc(b.w);
  return v;
}
__device__ __forceinline__ void gload16(const void* g, void* l) {
  __builtin_amdgcn_global_load_lds((const __attribute__((address_space(1))) void*)g,
                                   (__attribute__((address_space(3))) void*)l, 16, 0, 0);
}

#define DSR128(dst, addr, IMM) \
  asm volatile("ds_read_b128 %0, %1 offset:" IMM : "=v"(dst) : "v"(addr))
#define WAITLGKM(N) do { \
  asm volatile("s_waitcnt lgkmcnt(" #N ")" ::: "memory"); \
  __builtin_amdgcn_sched_barrier(0); } while (0)
#define WAITVM(N) do { \
  asm volatile("s_waitcnt vmcnt(" #N ")" ::: "memory"); \
  __builtin_amdgcn_sched_barrier(0); } while (0)

#define MFMA_BF16 __builtin_amdgcn_mfma_f32_16x16x32_bf16

// ---------------- prep: f32 weights -> bf16 MFMA B-fragment layout ----------------
__global__ __launch_bounds__(256, 4) void prep_kernel(
    const float* __restrict__ src, short* __restrict__ dst,
    int KT, int NP, int Nsrc) {
  __shared__ float tile[32 * 132];
  const int b = blockIdx.x;
  const int np = b % NP;
  const int kt = (b / NP) % KT;
  const int e  = b / (NP * KT);
  const int tid = threadIdx.x;
  const float* s = src + (size_t)e * KT * 32 * (size_t)Nsrc + (size_t)kt * 32 * Nsrc + np * 128;
#pragma unroll
  for (int i = 0; i < 4; i++) {
    const int idx = tid + i * 256;
    const int row = idx >> 5, c4 = idx & 31;
    float4 v = *(const float4*)(s + (size_t)row * Nsrc + c4 * 4);
    *(float4*)(tile + row * 132 + c4 * 4) = v;
  }
  __syncthreads();
  short* dbase = dst + ((size_t)(e * KT + kt) * (NP * 8) + np * 8) * 512;
#pragma unroll
  for (int i = 0; i < 2; i++) {
    const int c = tid + i * 256;
    const int lane = c & 63;
    const int nf = c >> 6;
    const int n = nf * 16 + (lane & 15);
    const int kb = (lane >> 4) * 8;
    s16x8 o;
#pragma unroll
    for (int j = 0; j < 8; j++) o[j] = bfc(tile[(kb + j) * 132 + n]);
    *(s16x8*)(dbase + (size_t)c * 8) = o;
  }
}

// ---------------- router ----------------
__global__ void router_kernel(const float* __restrict__ x, const float* __restrict__ wr,
                              int* __restrict__ cnt, int* __restrict__ lists,
                              float* __restrict__ wlists) {
  const int wave = threadIdx.x >> 6;
  const int lane = threadIdx.x & 63;
  const int t = blockIdx.x * 4 + wave;
  if (t >= NTOK) return;
  float acc[NEXP];
#pragma unroll
  for (int e = 0; e < NEXP; e++) acc[e] = 0.f;
  const float* xrow = x + (size_t)t * HID;
#pragma unroll
  for (int j = 0; j < HID / 256; j++) {
    const int k = j * 256 + lane * 4;
    float4 xv = *(const float4*)(xrow + k);
#pragma unroll
    for (int e = 0; e < NEXP; e++) {
      float4 wv = *(const float4*)(wr + e * HID + k);
      acc[e] += xv.x * wv.x + xv.y * wv.y + xv.z * wv.z + xv.w * wv.w;
    }
  }
#pragma unroll
  for (int e = 0; e < NEXP; e++) {
    float v = acc[e];
    for (int off = 32; off; off >>= 1) v += __shfl_xor(v, off, 64);
    acc[e] = v;
  }
  if (lane == 0) {
    float m = acc[0];
#pragma unroll
    for (int e = 1; e < NEXP; e++) m = fmaxf(m, acc[e]);
    float p[NEXP], s = 0.f;
#pragma unroll
    for (int e = 0; e < NEXP; e++) { p[e] = __expf(acc[e] - m); s += p[e]; }
    const float inv = 1.f / s;
    int e1 = 0; float b1 = p[0];
#pragma unroll
    for (int e = 1; e < NEXP; e++) if (p[e] > b1) { b1 = p[e]; e1 = e; }
    int e2 = -1; float b2 = -1.f;
#pragma unroll
    for (int e = 0; e < NEXP; e++) if (e != e1 && p[e] > b2) { b2 = p[e]; e2 = e; }
    const int pos1 = atomicAdd(&cnt[e1], 1);
    lists[e1 * NTOK + pos1] = t; wlists[e1 * NTOK + pos1] = b1 * inv;
    const int pos2 = atomicAdd(&cnt[e2], 1);
    lists[e2 * NTOK + pos2] = t; wlists[e2 * NTOK + pos2] = b2 * inv;
  }
}

__global__ void offsets_kernel(const int* __restrict__ cnt, int* __restrict__ poffs) {
  if (threadIdx.x == 0 && blockIdx.x == 0) {
    int o = 0;
#pragma unroll
    for (int e = 0; e < NEXP; e++) { poffs[e] = o; o += ((cnt[e] + 255) >> 8) << 8; }
    poffs[NEXP] = o;
  }
}

// ---------------- slotmap ----------------
__global__ void slotmap_kernel(const int* __restrict__ cnt, const int* __restrict__ poffs,
                               const int* __restrict__ lists, const float* __restrict__ wlists,
                               int* __restrict__ slotlist, int* __restrict__ tcnt,
                               int* __restrict__ tok2slot, float* __restrict__ w2) {
  const int e = blockIdx.x;
  const int c = cnt[e], base = poffs[e];
  for (int pos = threadIdx.x; pos < c; pos += blockDim.x) {
    const int tok = lists[e * NTOK + pos];
    const int slot = base + pos;
    slotlist[slot] = tok;
    const int j = atomicAdd(&tcnt[tok], 1);
    tok2slot[tok * 2 + j] = slot;
    w2[tok * 2 + j] = wlists[e * NTOK + pos];
  }
}

// ---------------- gather: x (f32) -> xg bf16 in A-fragment layout ----------------
__global__ __launch_bounds__(256, 4) void gather_kernel(
    const float* __restrict__ x, const int* __restrict__ slotlist,
    short* __restrict__ xg) {
  const int c = blockIdx.x * 256 + threadIdx.x;
  const int cl = c & 63;
  const int fragid = c >> 6;
  const int f = fragid & 15;
  const int kt = (fragid >> 4) & 63;
  const int gmt = fragid >> 10;
  const int tok = slotlist[gmt * 256 + f * 16 + (cl & 15)];
  const float* s = x + (size_t)tok * HID + kt * 32 + (cl >> 4) * 8;
  float4 a = *(const float4*)s, b = *(const float4*)(s + 4);
  *(s16x8*)(xg + (size_t)c * 8) = pk8(a, b);
}

// ---------------- gemm1: 256x128 tile, 8 waves, triple-buffer, counted vmcnt ------
__global__ __launch_bounds__(512, 1) void gemm1_kernel(
    const short* __restrict__ xg, const short* __restrict__ wgb,
    const short* __restrict__ wub, const int* __restrict__ cnt,
    const int* __restrict__ poffs, short* __restrict__ hfrag) {
  const int P = blockIdx.x;
  const int xcd = P & 7, slot = P >> 3;
  const int mt = slot & 31, jj = slot >> 5;
  const int g = jj * 8 + xcd;                 // (e,nt) group pinned to xcd
  const int e = g / NT1, nt = g % NT1;
  if (mt * 256 >= cnt[e]) return;
  const int gmt = (poffs[e] >> 8) + mt;
  const int tid = threadIdx.x;
  const int w = tid >> 6, lane = tid & 63;
  const int wm = w >> 1, wn = w & 1;

  // buffer (16384 shorts = 32KB): A 16 frags [0,8192), Bg [8192,12288), Bu [12288,16384)
  __shared__ __align__(16) short Lds[3 * 16384];
  const uint32_t ldsbase = (uint32_t)(uintptr_t)&Lds[0];

  const short* srcA  = xg  + (size_t)gmt * 64 * 16 * 512 + tid * 8;
  const short* srcBg = wgb + (((size_t)e * 64) * 352 + nt * 8) * 512 + tid * 8;
  const short* srcBu = wub + (((size_t)e * 64) * 352 + nt * 8) * 512 + tid * 8;

  const uint32_t roA = wm * 4096 + lane * 16;
  const uint32_t roB = 16384 + wn * 4096 + lane * 16;
  const uint32_t roU = 24576 + wn * 4096 + lane * 16;

  f32x4 accG[4][4], accU[4][4];
#pragma unroll
  for (int i = 0; i < 4; i++)
#pragma unroll
    for (int j = 0; j < 4; j++) {
      accG[i][j] = f32x4{0.f, 0.f, 0.f, 0.f};
      accU[i][j] = f32x4{0.f, 0.f, 0.f, 0.f};
    }

#define STG1(WB) do {                                                           \
    short* d = (short*)Lds + ((WB) >> 1);                                       \
    gload16(srcA,          d + w * 512);                                        \
    gload16(srcA + 4096,   d + 4096 + w * 512);                                 \
    gload16(srcBg,         d + 8192 + w * 512);                                 \
    gload16(srcBu,         d + 12288 + w * 512);                                \
    srcA += 8192; srcBg += 180224; srcBu += 180224; } while (0)

#define MMQ(NF)                                                                 \
  { __builtin_amdgcn_s_setprio(1);                                              \
    accG[0][NF] = MFMA_BF16(af[0], bg[NF], accG[0][NF], 0, 0, 0);               \
    accU[0][NF] = MFMA_BF16(af[0], bu[NF], accU[0][NF], 0, 0, 0);               \
    accG[1][NF] = MFMA_BF16(af[1], bg[NF], accG[1][NF], 0, 0, 0);               \
    accU[1][NF] = MFMA_BF16(af[1], bu[NF], accU[1][NF], 0, 0, 0);               \
    accG[2][NF] = MFMA_BF16(af[2], bg[NF], accG[2][NF], 0, 0, 0);               \
    accU[2][NF] = MFMA_BF16(af[2], bu[NF], accU[2][NF], 0, 0, 0);               \
    accG[3][NF] = MFMA_BF16(af[3], bg[NF], accG[3][NF], 0, 0, 0);               \
    accU[3][NF] = MFMA_BF16(af[3], bu[NF], accU[3][NF], 0, 0, 0);               \
    __builtin_amdgcn_s_setprio(0); }

#define G1_BODY(RB, WB, VMN, DOSTG)                                             \
  {                                                                             \
    WAITVM(VMN);                                                                \
    __builtin_amdgcn_s_barrier();                                               \
    const uint32_t rb = ldsbase + (RB);                                         \
    s16x8 af[4], bg[4], bu[4];                                                  \
    DSR128(bg[0], rb + roB, "0");    DSR128(bu[0], rb + roU, "0");              \
    DSR128(af[0], rb + roA, "0");    DSR128(af[1], rb + roA, "1024");           \
    DSR128(af[2], rb + roA, "2048"); DSR128(af[3], rb + roA, "3072");           \
    DSR128(bg[1], rb + roB, "1024"); DSR128(bu[1], rb + roU, "1024");           \
    DSR128(bg[2], rb + roB, "2048"); DSR128(bu[2], rb + roU, "2048");           \
    DSR128(bg[3], rb + roB, "3072"); DSR128(bu[3], rb + roU, "3072");           \
    if (DOSTG) { STG1(WB); }                                                    \
    WAITLGKM(6);                                                                \
    MMQ(0)                                                                      \
    WAITLGKM(4);                                                                \
    MMQ(1)                                                                      \
    WAITLGKM(2);                                                                \
    MMQ(2)                                                                      \
    WAITLGKM(0);                                                                \
    MMQ(3)                                                                      \
  }

  STG1(0);
  STG1(32768);
  for (int it = 0; it < 20; ++it) {          // t = 0..59
    G1_BODY(0,     65536, 4, 1)
    G1_BODY(32768, 0,     4, 1)
    G1_BODY(65536, 32768, 4, 1)
  }
  G1_BODY(0,     65536, 4, 1)                // t=60, stg 62 -> buf2
  G1_BODY(32768, 0,     4, 1)                // t=61, stg 63 -> buf0
  G1_BODY(65536, 0,     4, 0)                // t=62
  G1_BODY(0,     0,     0, 0)                // t=63
#undef G1_BODY
#undef MMQ
#undef STG1

  // epilogue: silu-gate, LDS transpose 256x128 (pad 136), store gemm2 A-frag layout
  short* tr = (short*)Lds;                   // 256*136*2B = 69632 <= 98304
  __syncthreads();
#pragma unroll
  for (int mf = 0; mf < 4; mf++)
#pragma unroll
    for (int reg = 0; reg < 4; reg++) {
      const int row = wm * 64 + mf * 16 + (lane >> 4) * 4 + reg;
#pragma unroll
      for (int nf = 0; nf < 4; nf++) {
        const int col = wn * 64 + nf * 16 + (lane & 15);
        const float gv = accG[mf][nf][reg];
        const float uv = accU[mf][nf][reg];
        tr[row * 136 + col] = bfc((gv / (1.f + __expf(-gv))) * uv);
      }
    }
  __syncthreads();
  short* hb = hfrag + (((size_t)gmt * 176 + nt * 4) * 16) * 512;
#pragma unroll
  for (int i = 0; i < 8; i++) {
    const int c = tid + i * 512;             // 0..4095
    const int cl = c & 63;
    const int f = (c >> 6) & 15;
    const int ktl = c >> 10;                 // 0..3
    const int rr = f * 16 + (cl & 15);
    s16x8 v = *(const s16x8*)(tr + rr * 136 + ktl * 32 + (cl >> 4) * 8);
    *(s16x8*)(hb + ((size_t)ktl * 16 + f) * 512 + cl * 8) = v;
  }
}

// ---------------- gemm2: 256x128 tile, 8 waves, triple-buffer, counted vmcnt ------
__global__ __launch_bounds__(512, 4) void gemm2_kernel(
    const short* __restrict__ hfrag, const short* __restrict__ wdb,
    const int* __restrict__ cnt, const int* __restrict__ poffs,
    __hip_bfloat16* __restrict__ pout) {
  const int P = blockIdx.x;
  const int xcd = P & 7, r = P >> 3;
  const int nt = r & 15, emq = r >> 4;
  const int gm = emq * 8 + xcd;              // m-tile pinned to xcd
  const int e = gm >> 5, mt = gm & 31;
  if (mt * 256 >= cnt[e]) return;
  const int gmt = (poffs[e] >> 8) + mt;
  const int n0 = nt * 128;
  const int tid = threadIdx.x;
  const int w = tid >> 6, lane = tid & 63;
  const int wm = w >> 1, wn = w & 1;

  // buffer (12288 shorts = 24KB): A 16 frags [0,8192), B 8 frags [8192,12288)
  __shared__ __align__(16) short Lds[3 * 12288];
  const uint32_t ldsbase = (uint32_t)(uintptr_t)&Lds[0];

  const short* srcA = hfrag + (size_t)gmt * 176 * 16 * 512 + tid * 8;
  const short* srcB = wdb + (((size_t)e * 176) * 128 + nt * 8) * 512 + tid * 8;

  const uint32_t roA = wm * 4096 + lane * 16;
  const uint32_t roB = 16384 + wn * 4096 + lane * 16;

  f32x4 acc[4][4];
#pragma unroll
  for (int i = 0; i < 4; i++)
#pragma unroll
    for (int j = 0; j < 4; j++) acc[i][j] = f32x4{0.f, 0.f, 0.f, 0.f};

#define STG2(WB) do {                                                           \
    short* d = (short*)Lds + ((WB) >> 1);                                       \
    gload16(srcA,        d + w * 512);                                          \
    gload16(srcA + 4096, d + 4096 + w * 512);                                   \
    gload16(srcB,        d + 8192 + w * 512);                                   \
    srcA += 8192; srcB += 65536; } while (0)

#define MMQ2(NF)                                                                \
  { __builtin_amdgcn_s_setprio(1);                                              \
    acc[0][NF] = MFMA_BF16(af[0], bf[NF], acc[0][NF], 0, 0, 0);                 \
    acc[1][NF] = MFMA_BF16(af[1], bf[NF], acc[1][NF], 0, 0, 0);                 \
    acc[2][NF] = MFMA_BF16(af[2], bf[NF], acc[2][NF], 0, 0, 0);                 \
    acc[3][NF] = MFMA_BF16(af[3], bf[NF], acc[3][NF], 0, 0, 0);                 \
    __builtin_amdgcn_s_setprio(0); }

#define G2_BODY(RB, WB, VMN, DOSTG)                                             \
  {                                                                             \
    WAITVM(VMN);                                                                \
    __builtin_amdgcn_s_barrier();                                               \
    const uint32_t rb = ldsbase + (RB);                                         \
    s16x8 af[4], bf[4];                                                         \
    DSR128(bf[0], rb + roB, "0");                                               \
    DSR128(af[0], rb + roA, "0");    DSR128(af[1], rb + roA, "1024");           \
    DSR128(af[2], rb + roA, "2048"); DSR128(af[3], rb + roA, "3072");           \
    DSR128(bf[1], rb + roB, "1024");                                            \
    DSR128(bf[2], rb + roB, "2048");                                            \
    DSR128(bf[3], rb + roB, "3072");                                            \
    if (DOSTG) { STG2(WB); }                                                    \
    WAITLGKM(3);                                                                \
    MMQ2(0)                                                                     \
    WAITLGKM(2);                                                                \
    MMQ2(1)                                                                     \
    WAITLGKM(1);                                                                \
    MMQ2(2)                                                                     \
    WAITLGKM(0);                                                                \
    MMQ2(3)                                                                     \
  }

  STG2(0);
  STG2(24576);
  for (int it = 0; it < 58; ++it) {          // t = 0..173
    G2_BODY(0,     49152, 3, 1)
    G2_BODY(24576, 0,     3, 1)
    G2_BODY(49152, 24576, 3, 1)
  }
  G2_BODY(0,     0, 3, 0)                    // t=174
  G2_BODY(24576, 0, 0, 0)                    // t=175
#undef G2_BODY
#undef MMQ2
#undef STG2

  const int slotb = poffs[e] + mt * 256;
#pragma unroll
  for (int mf = 0; mf < 4; mf++) {
#pragma unroll
    for (int reg = 0; reg < 4; reg++) {
      const int row = wm * 64 + mf * 16 + (lane >> 4) * 4 + reg;
      __hip_bfloat16* op = pout + (size_t)(slotb + row) * HID + n0 + wn * 64 + (lane & 15);
#pragma unroll
      for (int nf = 0; nf < 4; nf++)
        op[nf * 16] = __float2bfloat16(acc[mf][nf][reg]);
    }
  }
}

// ---------------- combine ----------------
__global__ __launch_bounds__(256, 8) void combine_kernel(
    const __hip_bfloat16* __restrict__ pout, const int* __restrict__ tok2slot,
    const float* __restrict__ w2, float* __restrict__ out) {
  const int t = blockIdx.x;
  const int s0 = tok2slot[2 * t], s1 = tok2slot[2 * t + 1];
  const float w0 = w2[2 * t], w1 = w2[2 * t + 1];
  const short* p0 = (const short*)pout + (size_t)s0 * HID;
  const short* p1 = (const short*)pout + (size_t)s1 * HID;
  float* o = out + (size_t)t * HID;
  const int i = threadIdx.x;
  s16x8 a = *(const s16x8*)(p0 + i * 8);
  s16x8 b = *(const s16x8*)(p1 + i * 8);
  float4 r0, r1;
  r0.x = w0 * b2f(a[0]) + w1 * b2f(b[0]);
  r0.y = w0 * b2f(a[1]) + w1 * b2f(b[1]);
  r0.z = w0 * b2f(a[2]) + w1 * b2f(b[2]);
  r0.w = w0 * b2f(a[3]) + w1 * b2f(b[3]);
  r1.x = w0 * b2f(a[4]) + w1 * b2f(b[4]);
  r1.y = w0 * b2f(a[5]) + w1 * b2f(b[5]);
  r1.z = w0 * b2f(a[6]) + w1 * b2f(b[6]);
  r1.w = w0 * b2f(a[7]) + w1 * b2f(b[7]);
  *(float4*)(o + i * 8) = r0;
  *(float4*)(o + i * 8 + 4) = r1;
}

extern "C" void kernel_launch(void* const* d_in, const int* in_sizes, int n_in,
                              void* d_out, int out_size, void* d_ws, size_t ws_size,
                              hipStream_t stream) {
  const float* x  = (const float*)d_in[0];
  const float* wr = (const float*)d_in[1];
  const float* wg = (const float*)d_in[2];
  const float* wu = (const float*)d_in[3];
  const float* wd = (const float*)d_in[4];
  float* out = (float*)d_out;
  char* ws = (char*)d_ws;

  int* cnt      = (int*)ws;
  int* poffs    = (int*)(ws + 64);
  int* tcnt     = (int*)(ws + TCNT_OFF);
  int* slotlist = (int*)(ws + SLOT_OFF);
  int* tok2slot = (int*)(ws + T2S_OFF);
  float* w2     = (float*)(ws + W2_OFF);
  int* lists    = (int*)(ws + LISTS_OFF);
  float* wlists = (float*)(ws + WL_OFF);
  short* wgb    = (short*)(ws + WG_OFF);
  short* wub    = (short*)(ws + WU_OFF);
  short* wdb    = (short*)(ws + WG_OFF);     // reuses wgb region (after gemm1)
  short* hfrag  = (short*)(ws + HF_OFF);
  short* xg     = (short*)(ws + XG_OFF);
  __hip_bfloat16* pout = (__hip_bfloat16*)(ws + XG_OFF);  // reuses xg (after gemm1)

  hipMemsetAsync(ws, 0, 256, stream);
  hipMemsetAsync(ws + TCNT_OFF, 0, 32768, stream);
  hipMemsetAsync(ws + SLOT_OFF, 0, 73728, stream);

  router_kernel<<<NTOK / 4, 256, 0, stream>>>(x, wr, cnt, lists, wlists);
  offsets_kernel<<<1, 64, 0, stream>>>(cnt, poffs);
  slotmap_kernel<<<NEXP, 256, 0, stream>>>(cnt, poffs, lists, wlists, slotlist, tcnt, tok2slot, w2);
  gather_kernel<<<18432, 256, 0, stream>>>(x, slotlist, xg);
  prep_kernel<<<NEXP * 64 * 44, 256, 0, stream>>>(wg, wgb, 64, 44, INTR);
  prep_kernel<<<NEXP * 64 * 44, 256, 0, stream>>>(wu, wub, 64, 44, INTR);
  gemm1_kernel<<<8 * 32 * NT1, 512, 0, stream>>>(xg, wgb, wub, cnt, poffs, hfrag);
  prep_kernel<<<NEXP * 176 * 16, 256, 0, stream>>>(wd, wdb, 176, 16, HID);
  gemm2_kernel<<<8 * 16 * 32, 512, 0, stream>>>(hfrag, wdb, cnt, poffs, pout);
  combine_kernel<<<NTOK, 256, 0, stream>>>(pout, tok2slot, w2, out);
}